// Round 6
// baseline (97.150 us; speedup 1.0000x reference)
//
#include <hip/hip_runtime.h>
#include <math.h>

#define NFRM 4
#define NFACE 512
#define TT 256
#define REC 32                      // floats per face record (pow2 for addressing)
#define TANF32 0.413980342966f      // float32(tan(0.785/2))
#define LOG1M_CONST -9.21017456f    // float32(log1p(-float32(0.9999)))
#define D2_CUTOFF 0.004286f         // exp(-7000*d2) < 1.2e-13 beyond this
#define MARGIN 0.0656f              // MARGIN^2 = 0.004303 > D2_CUTOFF

typedef float v2f __attribute__((ext_vector_type(2)));

__device__ __forceinline__ float fm(float a, float b) { return __fmul_rn(a, b); }
__device__ __forceinline__ float fa2(float a, float b) { return __fadd_rn(a, b); }
__device__ __forceinline__ float fs2(float a, float b) { return __fsub_rn(a, b); }
__device__ __forceinline__ float fd2(float a, float b) { return __fdiv_rn(a, b); }

// Record layout (REC=32):
// [4]flag (1=ok,2=degenerate-area) [5]sgn(area) [6]inv_area
// [8]ax [9]ay [10]e2x [11]e2y  [12]bx [13]by [14]e0x [15]e0y
// [16]cx [17]cy [18]e1x [19]e1y [20]fz0 [21]fz1 [22]fz2
// [24]invL2(e2) [25]invL2(e0) [26]invL2(e1)

// ---------------- Kernel 1: per-(frame,face) geometry setup ----------------
__global__ void setup_kernel(const float* __restrict__ trans,
                             const float* __restrict__ quat,
                             const float* __restrict__ uverts,
                             const int* __restrict__ faces,
                             float* __restrict__ recs,
                             float4* __restrict__ bbox4) {
    int idx = blockIdx.x * blockDim.x + threadIdx.x;
    if (idx >= NFRM * NFACE) return;
    int frame = idx >> 9;
    int face  = idx & (NFACE - 1);

    float qw = quat[frame * 4 + 0];
    float qx = quat[frame * 4 + 1];
    float qy = quat[frame * 4 + 2];
    float qz = quat[frame * 4 + 3];
    float qn = sqrtf(fa2(fa2(fa2(fm(qw, qw), fm(qx, qx)), fm(qy, qy)), fm(qz, qz)));
    qw = fd2(qw, qn); qx = fd2(qx, qn); qy = fd2(qy, qn); qz = fd2(qz, qn);

    float r00 = fs2(1.f, fm(2.f, fa2(fm(qy, qy), fm(qz, qz))));
    float r01 = fm(2.f, fs2(fm(qx, qy), fm(qw, qz)));
    float r02 = fm(2.f, fa2(fm(qx, qz), fm(qw, qy)));
    float r10 = fm(2.f, fa2(fm(qx, qy), fm(qw, qz)));
    float r11 = fs2(1.f, fm(2.f, fa2(fm(qx, qx), fm(qz, qz))));
    float r12 = fm(2.f, fs2(fm(qy, qz), fm(qw, qx)));
    float r20 = fm(2.f, fs2(fm(qx, qz), fm(qw, qy)));
    float r21 = fm(2.f, fa2(fm(qy, qz), fm(qw, qx)));
    float r22 = fs2(1.f, fm(2.f, fa2(fm(qx, qx), fm(qy, qy))));

    float tx = trans[frame * 3 + 0];
    float ty = trans[frame * 3 + 1];
    float tz = trans[frame * 3 + 2];

    float camx[3], camy[3], camz[3], ix[3], iy[3];
    for (int k = 0; k < 3; ++k) {
        int vi = faces[face * 3 + k];
        float ux = uverts[vi * 3 + 0];
        float uy = uverts[vi * 3 + 1];
        float uz = uverts[vi * 3 + 2];
        float X = fa2(fa2(fa2(fm(r00, ux), fm(r01, uy)), fm(r02, uz)), tx);
        float Y = fa2(fa2(fa2(fm(r10, ux), fm(r11, uy)), fm(r12, uz)), ty);
        float Z = fs2(fa2(fa2(fa2(fm(r20, ux), fm(r21, uy)), fm(r22, uz)), tz), 2.0f);
        float negz = -Z;
        camx[k] = X; camy[k] = Y; camz[k] = Z;
        ix[k] = fd2(fd2(X, TANF32), negz);
        iy[k] = fd2(fd2(Y, TANF32), negz);
    }

    // back-face: fnz>0 <=> nz>0 (norm denominator strictly positive)
    float e1cx = fs2(camx[1], camx[0]), e1cy = fs2(camy[1], camy[0]);
    float e2cx = fs2(camx[2], camx[0]), e2cy = fs2(camy[2], camy[0]);
    float nz = fs2(fm(e1cx, e2cy), fm(e1cy, e2cx));

    float ax = ix[0], ay = iy[0], bx = ix[1], by = iy[1], cx = ix[2], cy = iy[2];
    float area = fs2(fm(fs2(cx, ax), fs2(by, ay)), fm(fs2(cy, ay), fs2(bx, ax)));
    bool areaok = fabsf(area) > 1e-10f;
    float area_s = (fabsf(area) < 1e-10f) ? 1e-10f : area;

    float e0x = fs2(cx, bx), e0y = fs2(cy, by);
    float e1x = fs2(ax, cx), e1y = fs2(ay, cy);
    float e2x = fs2(bx, ax), e2y = fs2(by, ay);

    float* r = recs + (size_t)idx * REC;
    r[0] = 0.f; r[1] = 0.f; r[2] = 0.f; r[3] = 0.f;
    r[4] = areaok ? 1.f : 2.f;
    r[5] = (area_s >= 0.f) ? 1.f : -1.f;
    r[6] = fd2(1.0f, area_s);
    r[7] = 0.f;
    r[8]  = ax; r[9]  = ay; r[10] = e2x; r[11] = e2y;
    r[12] = bx; r[13] = by; r[14] = e0x; r[15] = e0y;
    r[16] = cx; r[17] = cy; r[18] = e1x; r[19] = e1y;
    r[20] = camz[0]; r[21] = camz[1]; r[22] = camz[2]; r[23] = 0.f;
    r[24] = fd2(1.0f, fa2(fa2(fm(e2x, e2x), fm(e2y, e2y)), 1e-12f));
    r[25] = fd2(1.0f, fa2(fa2(fm(e0x, e0x), fm(e0y, e0y)), 1e-12f));
    r[26] = fd2(1.0f, fa2(fa2(fm(e1x, e1x), fm(e1y, e1y)), 1e-12f));
    r[27] = 0.f; r[28] = 0.f; r[29] = 0.f; r[30] = 0.f; r[31] = 0.f;

    float4 bb;
    if (nz > 0.f) {
        bb.x = fminf(fminf(ax, bx), cx);
        bb.y = fmaxf(fmaxf(ax, bx), cx);
        bb.z = fminf(fminf(ay, by), cy);
        bb.w = fmaxf(fmaxf(ay, by), cy);
    } else {  // culled: impossible bbox, never passes the tile test
        bb.x = 1e30f; bb.y = -1e30f; bb.z = 1e30f; bb.w = -1e30f;
    }
    bbox4[idx] = bb;
}

// Uniform face record (scalar-loaded; ~20 SGPRs)
struct FRec {
    float flag, sgn, ia;
    float ax, ay, e2x, e2y, bx, by, e0x, e0y, cx, cy, e1x, e1y;
    float z0, z1, z2, iL2, iL0, iL1;
};
__device__ __forceinline__ FRec loadRec(const float* __restrict__ recF, int f) {
    const float* r = recF + ((size_t)f << 5);
    FRec o;
    o.flag = r[4];  o.sgn = r[5];  o.ia  = r[6];
    o.ax = r[8];  o.ay = r[9];  o.e2x = r[10]; o.e2y = r[11];
    o.bx = r[12]; o.by = r[13]; o.e0x = r[14]; o.e0y = r[15];
    o.cx = r[16]; o.cy = r[17]; o.e1x = r[18]; o.e1y = r[19];
    o.z0 = r[20]; o.z1 = r[21]; o.z2 = r[22];
    o.iL2 = r[24]; o.iL0 = r[25]; o.iL1 = r[26];
    return o;
}

// ---------------- Kernel 2: rasterize + shade ----------------
// 1024 blocks; block = 256 threads = 64 pixels (8x8 tile) x 4 waves.
// Ballot-compact tile face list (ascending), split contiguously over waves,
// software-pipeline the uniform record loads, packed-fp32 segment math.
__global__ __launch_bounds__(256, 4) void raster_kernel(
        const float* __restrict__ recs,
        const float4* __restrict__ bbox4,
        const float* __restrict__ ffeat,
        const float* __restrict__ tex,
        float* __restrict__ out,
        float* __restrict__ softbuf) {
    __shared__ int s_list[NFACE];
    __shared__ int s_cnt[4];
    __shared__ float s_score[256], s_w0[256], s_w1[256], s_w2[256], s_acc[256];
    __shared__ int s_best[256];

    int b = blockIdx.x;
    int tileIdx = (int)(__brev((unsigned)(b & 255)) >> 24);  // bit-reverse swizzle
    int frame = b >> 8;
    int txo = (tileIdx & 15) * 8;
    int tyo = (tileIdx >> 4) * 8;

    int chunk = threadIdx.x >> 6;
    int lane  = threadIdx.x & 63;
    int w = txo + (lane & 7);
    int h = tyo + (lane >> 3);
    int p = h * 128 + w;
    float px = (w + 0.5f) * (1.0f / 64.0f) - 1.0f;   // exact, == np value
    float py = 1.0f - (h + 0.5f) * (1.0f / 64.0f);

    float txmin = (txo + 0.5f) * (1.0f / 64.0f) - 1.0f - MARGIN;
    float txmax = (txo + 7.5f) * (1.0f / 64.0f) - 1.0f + MARGIN;
    float tymin = 1.0f - (tyo + 7.5f) * (1.0f / 64.0f) - MARGIN;
    float tymax = 1.0f - (tyo + 0.5f) * (1.0f / 64.0f) + MARGIN;

    // ---- Phase 1: bin faces into s_list (ascending face order) ----
    const float4* bbF = bbox4 + frame * NFACE;
    {
        float4 b0 = bbF[chunk * 128 + lane];
        float4 b1 = bbF[chunk * 128 + 64 + lane];
        bool p0 = (b0.x <= txmax) & (b0.y >= txmin) & (b0.z <= tymax) & (b0.w >= tymin);
        bool p1 = (b1.x <= txmax) & (b1.y >= txmin) & (b1.z <= tymax) & (b1.w >= tymin);
        unsigned long long m0 = __ballot(p0);
        unsigned long long m1 = __ballot(p1);
        if (lane == 0) s_cnt[chunk] = __popcll(m0) + __popcll(m1);
        __syncthreads();
        int base = 0;
        for (int c = 0; c < chunk; ++c) base += s_cnt[c];
        unsigned long long ltmask = (1ull << lane) - 1ull;
        if (p0) s_list[base + __popcll(m0 & ltmask)] = chunk * 128 + lane;
        if (p1) s_list[base + __popcll(m0) + __popcll(m1 & ltmask)] = chunk * 128 + 64 + lane;
        __syncthreads();
    }
    int total = s_cnt[0] + s_cnt[1] + s_cnt[2] + s_cnt[3];

    // ---- Phase 2: process list segment [lo,hi), ascending, pipelined ----
    const float* recF = recs + (size_t)frame * NFACE * REC;
    float bestScore = -1e30f;
    int best = -1;
    float bw0 = 0.f, bw1 = 0.f, bw2 = 0.f;
    float acc = 0.f;

    int lo = (total * chunk) >> 2;
    int hi = (total * (chunk + 1)) >> 2;
    if (lo < hi) {
        int f_cur = __builtin_amdgcn_readfirstlane(s_list[lo]);
        FRec cur = loadRec(recF, f_cur);
        for (int i = lo; i < hi; ++i) {
            // prefetch next record while computing current
            int nj = (i + 1 < hi) ? (i + 1) : i;
            int f_nxt = __builtin_amdgcn_readfirstlane(s_list[nj]);
            FRec nxt = loadRec(recF, f_nxt);

            float apx = fs2(px, cur.ax), apy = fs2(py, cur.ay);
            float bpx = fs2(px, cur.bx), bpy = fs2(py, cur.by);
            float cpx = fs2(px, cur.cx), cpy = fs2(py, cur.cy);
            // numerators in np's exact expression form (sign-exact inside test)
            float n0 = fs2(fm(bpx, cur.e0y), fm(bpy, cur.e0x));
            float n1 = fs2(fm(cpx, cur.e1y), fm(cpy, cur.e1x));
            float n2 = fs2(fm(apx, cur.e2y), fm(apy, cur.e2x));
            float sgn = cur.sgn;
            bool inside = (cur.flag == 1.f) & (fm(n0, sgn) >= 0.f)
                        & (fm(n1, sgn) >= 0.f) & (fm(n2, sgn) >= 0.f);
            if (inside) {
                float ia = cur.ia;
                float w0 = fm(n0, ia), w1v = fm(n1, ia), w2v = fm(n2, ia);
                float zpix = fa2(fa2(fm(w0, cur.z0), fm(w1v, cur.z1)), fm(w2v, cur.z2));
                if (zpix > bestScore) {  // strict > == np argmax first-max
                    bestScore = zpix; best = f_cur; bw0 = w0; bw1 = w1v; bw2 = w2v;
                }
                acc += LOG1M_CONST;      // d2=0 -> prob=0.9999
            } else {
                // packed-fp32 segment distances (continuous path, fma ok)
                v2f ap = {apx, apy}, bp = {bpx, bpy}, cp = {cpx, cpy};
                v2f e2 = {cur.e2x, cur.e2y};
                v2f e0 = {cur.e0x, cur.e0y};
                v2f e1 = {cur.e1x, cur.e1y};
                v2f pa = ap * e2, pb = bp * e0, pc = cp * e1;
                float t0 = fminf(fmaxf((pa.x + pa.y) * cur.iL2, 0.f), 1.f);
                float t1 = fminf(fmaxf((pb.x + pb.y) * cur.iL0, 0.f), 1.f);
                float t2 = fminf(fmaxf((pc.x + pc.y) * cur.iL1, 0.f), 1.f);
                v2f d0 = ap - t0 * e2;
                v2f d1 = bp - t1 * e0;
                v2f d2v = cp - t2 * e1;
                v2f q0 = d0 * d0, q1 = d1 * d1, q2 = d2v * d2v;
                float d2 = fminf(fminf(q0.x + q0.y, q1.x + q1.y), q2.x + q2.y);
                if (d2 < D2_CUTOFF) {
                    float pr = fminf(__expf(d2 * -7000.f), 0.9999f);
                    acc += __logf(1.0f - pr);
                }
            }
            cur = nxt; f_cur = f_nxt;
        }
    }

    s_score[threadIdx.x] = bestScore;
    s_best[threadIdx.x] = best;
    s_w0[threadIdx.x] = bw0; s_w1[threadIdx.x] = bw1; s_w2[threadIdx.x] = bw2;
    s_acc[threadIdx.x] = acc;
    __syncthreads();

    if (threadIdx.x < 64) {
        int i = threadIdx.x;   // chunk-0 thread: same pixel (p, px, py)
        bestScore = s_score[i]; best = s_best[i];
        bw0 = s_w0[i]; bw1 = s_w1[i]; bw2 = s_w2[i];
        acc = s_acc[i];
        for (int c = 1; c < 4; ++c) {   // ascending chunk order keeps first-max
            int j = c * 64 + i;
            float sc = s_score[j];
            if (sc > bestScore) {
                bestScore = sc; best = s_best[j];
                bw0 = s_w0[j]; bw1 = s_w1[j]; bw2 = s_w2[j];
            }
            acc += s_acc[j];
        }
        float fu = 0.f, fv = 0.f;
        if (best >= 0) {
            const float* fb = ffeat + best * 6;
            fu = bw0 * fb[0] + bw1 * fb[2] + bw2 * fb[4];
            fv = bw0 * fb[1] + bw1 * fb[3] + bw2 * fb[5];
        }
        float u = fminf(fmaxf(fu, 0.f), 1.f);
        float v = fminf(fmaxf(fv, 0.f), 1.f);
        float x = u * (float)TT - 0.5f;
        float y = (1.0f - v) * (float)TT - 0.5f;
        float x0f = floorf(x), y0f = floorf(y);
        float wx = x - x0f, wy = y - y0f;
        int x0 = min(max((int)x0f, 0), TT - 1);
        int x1 = min(x0 + 1, TT - 1);
        int y0 = min(max((int)y0f, 0), TT - 1);
        int y1 = min(y0 + 1, TT - 1);
        size_t obase = (size_t)frame * 5 * 16384 + p;
        for (int c = 0; c < 3; ++c) {
            const float* tc = tex + c * (TT * TT);
            float t00 = tc[y0 * TT + x0];
            float t01 = tc[y0 * TT + x1];
            float t10 = tc[y1 * TT + x0];
            float t11 = tc[y1 * TT + x1];
            float rgb = (1.f - wy) * ((1.f - wx) * t00 + wx * t01)
                      + wy * ((1.f - wx) * t10 + wx * t11);
            out[obase + (size_t)c * 16384] = rgb;
        }
        int redw = (best >= 0) ? best : (NFACE - 1);
        const float* rr = recF + ((size_t)redw << 5);
        float depth = fd2(fa2(fa2(rr[20], rr[21]), rr[22]), 3.0f);
        out[obase + 4ull * 16384] = depth;
        float soft = 1.0f - __expf(acc);
        softbuf[frame * 16384 + p] = soft;
    }
}

// ---------------- Kernel 3: 7x7 min-pool (pad = +inf identity) ----------------
__global__ void minpool_kernel(const float* __restrict__ softbuf,
                               float* __restrict__ out) {
    int idx = blockIdx.x * 256 + threadIdx.x;
    if (idx >= NFRM * 16384) return;
    int frame = idx >> 14;
    int p = idx & 16383;
    int h = p >> 7, w = p & 127;
    const float* sb = softbuf + frame * 16384;
    float m = INFINITY;
    int h0 = max(h - 3, 0), h1 = min(h + 3, 127);
    int w0 = max(w - 3, 0), w1 = min(w + 3, 127);
    for (int hh = h0; hh <= h1; ++hh)
        for (int ww = w0; ww <= w1; ++ww)
            m = fminf(m, sb[hh * 128 + ww]);
    out[(size_t)frame * 5 * 16384 + 3ull * 16384 + p] = m;
}

// ---------------- launch ----------------
extern "C" void kernel_launch(void* const* d_in, const int* in_sizes, int n_in,
                              void* d_out, int out_size, void* d_ws, size_t ws_size,
                              hipStream_t stream) {
    const float* trans  = (const float*)d_in[0]; // (1,1,4,3)
    const float* quat   = (const float*)d_in[1]; // (1,4,4)
    const float* uverts = (const float*)d_in[2]; // (1,256,3)
    const float* ffeat  = (const float*)d_in[3]; // (1,512,3,2)
    const float* tex    = (const float*)d_in[4]; // (1,3,256,256)
    const int*   faces  = (const int*)d_in[5];   // (512,3)
    float* out = (float*)d_out;                  // (1,4,1,5,128,128) fp32

    float* recs    = (float*)d_ws;                         // 4*512*32 f = 256 KB
    float4* bbox4  = (float4*)(recs + NFRM * NFACE * REC); // 4*512 f4 = 32 KB
    float* softbuf = (float*)(bbox4 + NFRM * NFACE);       // 4*16384 floats

    setup_kernel<<<(NFRM * NFACE + 255) / 256, 256, 0, stream>>>(
        trans, quat, uverts, faces, recs, bbox4);
    raster_kernel<<<NFRM * 256, 256, 0, stream>>>(
        recs, bbox4, ffeat, tex, out, softbuf);
    minpool_kernel<<<(NFRM * 16384) / 256, 256, 0, stream>>>(softbuf, out);
}

// Round 7
// 94.008 us; speedup vs baseline: 1.0334x; 1.0334x over previous
//
#include <hip/hip_runtime.h>
#include <math.h>

#define NFRM 4
#define NFACE 512
#define TT 256
#define REC 32                      // floats per face record (pow2 for addressing)
#define TANF32 0.413980342966f      // float32(tan(0.785/2))
#define LOG1M_CONST -9.21017456f    // float32(log1p(-float32(0.9999)))
#define D2_CUTOFF 0.004286f         // exp(-7000*d2) < 1.2e-13 beyond this
#define MARGIN 0.0656f              // MARGIN^2 = 0.004303 > D2_CUTOFF
#define MARGIN2 0.00430336f

__device__ __forceinline__ float fm(float a, float b) { return __fmul_rn(a, b); }
__device__ __forceinline__ float fa2(float a, float b) { return __fadd_rn(a, b); }
__device__ __forceinline__ float fs2(float a, float b) { return __fsub_rn(a, b); }
__device__ __forceinline__ float fd2(float a, float b) { return __fdiv_rn(a, b); }

// Record layout (REC=32):
// [4]flag (1=ok,2=degenerate-area) [5]sgn(area) [6]inv_area
// [8]ax [9]ay [10]e2x [11]e2y  [12]bx [13]by [14]e0x [15]e0y
// [16]cx [17]cy [18]e1x [19]e1y [20]fz0 [21]fz1 [22]fz2
// [24]invL2(e2) [25]invL2(e0) [26]invL2(e1)

// ---------------- Kernel 1: per-(frame,face) geometry setup ----------------
__global__ void setup_kernel(const float* __restrict__ trans,
                             const float* __restrict__ quat,
                             const float* __restrict__ uverts,
                             const int* __restrict__ faces,
                             float* __restrict__ recs,
                             float4* __restrict__ bbox4) {
    int idx = blockIdx.x * blockDim.x + threadIdx.x;
    if (idx >= NFRM * NFACE) return;
    int frame = idx >> 9;
    int face  = idx & (NFACE - 1);

    float qw = quat[frame * 4 + 0];
    float qx = quat[frame * 4 + 1];
    float qy = quat[frame * 4 + 2];
    float qz = quat[frame * 4 + 3];
    float qn = sqrtf(fa2(fa2(fa2(fm(qw, qw), fm(qx, qx)), fm(qy, qy)), fm(qz, qz)));
    qw = fd2(qw, qn); qx = fd2(qx, qn); qy = fd2(qy, qn); qz = fd2(qz, qn);

    float r00 = fs2(1.f, fm(2.f, fa2(fm(qy, qy), fm(qz, qz))));
    float r01 = fm(2.f, fs2(fm(qx, qy), fm(qw, qz)));
    float r02 = fm(2.f, fa2(fm(qx, qz), fm(qw, qy)));
    float r10 = fm(2.f, fa2(fm(qx, qy), fm(qw, qz)));
    float r11 = fs2(1.f, fm(2.f, fa2(fm(qx, qx), fm(qz, qz))));
    float r12 = fm(2.f, fs2(fm(qy, qz), fm(qw, qx)));
    float r20 = fm(2.f, fs2(fm(qx, qz), fm(qw, qy)));
    float r21 = fm(2.f, fa2(fm(qy, qz), fm(qw, qx)));
    float r22 = fs2(1.f, fm(2.f, fa2(fm(qx, qx), fm(qy, qy))));

    float tx = trans[frame * 3 + 0];
    float ty = trans[frame * 3 + 1];
    float tz = trans[frame * 3 + 2];

    float camx[3], camy[3], camz[3], ix[3], iy[3];
    for (int k = 0; k < 3; ++k) {
        int vi = faces[face * 3 + k];
        float ux = uverts[vi * 3 + 0];
        float uy = uverts[vi * 3 + 1];
        float uz = uverts[vi * 3 + 2];
        float X = fa2(fa2(fa2(fm(r00, ux), fm(r01, uy)), fm(r02, uz)), tx);
        float Y = fa2(fa2(fa2(fm(r10, ux), fm(r11, uy)), fm(r12, uz)), ty);
        float Z = fs2(fa2(fa2(fa2(fm(r20, ux), fm(r21, uy)), fm(r22, uz)), tz), 2.0f);
        float negz = -Z;
        camx[k] = X; camy[k] = Y; camz[k] = Z;
        ix[k] = fd2(fd2(X, TANF32), negz);
        iy[k] = fd2(fd2(Y, TANF32), negz);
    }

    // back-face: fnz>0 <=> nz>0 (norm denominator strictly positive)
    float e1cx = fs2(camx[1], camx[0]), e1cy = fs2(camy[1], camy[0]);
    float e2cx = fs2(camx[2], camx[0]), e2cy = fs2(camy[2], camy[0]);
    float nz = fs2(fm(e1cx, e2cy), fm(e1cy, e2cx));

    float ax = ix[0], ay = iy[0], bx = ix[1], by = iy[1], cx = ix[2], cy = iy[2];
    float area = fs2(fm(fs2(cx, ax), fs2(by, ay)), fm(fs2(cy, ay), fs2(bx, ax)));
    bool areaok = fabsf(area) > 1e-10f;
    float area_s = (fabsf(area) < 1e-10f) ? 1e-10f : area;

    float e0x = fs2(cx, bx), e0y = fs2(cy, by);
    float e1x = fs2(ax, cx), e1y = fs2(ay, cy);
    float e2x = fs2(bx, ax), e2y = fs2(by, ay);

    float* r = recs + (size_t)idx * REC;
    r[0] = 0.f; r[1] = 0.f; r[2] = 0.f; r[3] = 0.f;
    r[4] = areaok ? 1.f : 2.f;
    r[5] = (area_s >= 0.f) ? 1.f : -1.f;
    r[6] = fd2(1.0f, area_s);
    r[7] = 0.f;
    r[8]  = ax; r[9]  = ay; r[10] = e2x; r[11] = e2y;
    r[12] = bx; r[13] = by; r[14] = e0x; r[15] = e0y;
    r[16] = cx; r[17] = cy; r[18] = e1x; r[19] = e1y;
    r[20] = camz[0]; r[21] = camz[1]; r[22] = camz[2]; r[23] = 0.f;
    r[24] = fd2(1.0f, fa2(fa2(fm(e2x, e2x), fm(e2y, e2y)), 1e-12f));
    r[25] = fd2(1.0f, fa2(fa2(fm(e0x, e0x), fm(e0y, e0y)), 1e-12f));
    r[26] = fd2(1.0f, fa2(fa2(fm(e1x, e1x), fm(e1y, e1y)), 1e-12f));
    r[27] = 0.f; r[28] = 0.f; r[29] = 0.f; r[30] = 0.f; r[31] = 0.f;

    float4 bb;
    if (nz > 0.f) {
        bb.x = fminf(fminf(ax, bx), cx);
        bb.y = fmaxf(fmaxf(ax, bx), cx);
        bb.z = fminf(fminf(ay, by), cy);
        bb.w = fmaxf(fmaxf(ay, by), cy);
    } else {  // culled: impossible bbox, never passes the tile test
        bb.x = 1e30f; bb.y = -1e30f; bb.z = 1e30f; bb.w = -1e30f;
    }
    bbox4[idx] = bb;
}

// ---------------- Kernel 2: rasterize + shade ----------------
// 1024 blocks; block = 256 threads = 64 pixels (8x8 tile) x 4 waves.
// Phase 1: bbox ballot-compaction. Phase 1b: exact edge-halfplane-vs-tile
// rejection (conservative raster corner trick) — kills big-triangle/far-body
// faces whose bbox covers the tile. Phase 2: face loop on the refined list.
__global__ __launch_bounds__(256, 4) void raster_kernel(
        const float* __restrict__ recs,
        const float4* __restrict__ bbox4,
        const float* __restrict__ ffeat,
        const float* __restrict__ tex,
        float* __restrict__ out,
        float* __restrict__ softbuf) {
    __shared__ int s_listA[NFACE];
    __shared__ int s_listB[NFACE];
    __shared__ int s_cnt[4];
    __shared__ float s_score[256], s_w0[256], s_w1[256], s_w2[256], s_acc[256];
    __shared__ int s_best[256];

    int b = blockIdx.x;
    int tileIdx = (int)(__brev((unsigned)(b & 255)) >> 24);  // bit-reverse swizzle
    int frame = b >> 8;
    int txo = (tileIdx & 15) * 8;
    int tyo = (tileIdx >> 4) * 8;

    int chunk = threadIdx.x >> 6;
    int lane  = threadIdx.x & 63;
    int w = txo + (lane & 7);
    int h = tyo + (lane >> 3);
    int p = h * 128 + w;
    float px = (w + 0.5f) * (1.0f / 64.0f) - 1.0f;   // exact, == np value
    float py = 1.0f - (h + 0.5f) * (1.0f / 64.0f);

    // pixel-center tile extents
    float X0 = (txo + 0.5f) * (1.0f / 64.0f) - 1.0f;
    float X1 = (txo + 7.5f) * (1.0f / 64.0f) - 1.0f;
    float Y0 = 1.0f - (tyo + 7.5f) * (1.0f / 64.0f);
    float Y1 = 1.0f - (tyo + 0.5f) * (1.0f / 64.0f);
    float txmin = X0 - MARGIN, txmax = X1 + MARGIN;
    float tymin = Y0 - MARGIN, tymax = Y1 + MARGIN;

    const float* recF = recs + (size_t)frame * NFACE * REC;
    unsigned long long ltmask = (1ull << lane) - 1ull;

    // ---- Phase 1: bbox binning into s_listA (ascending face order) ----
    int totalA;
    {
        const float4* bbF = bbox4 + frame * NFACE;
        float4 b0 = bbF[chunk * 128 + lane];
        float4 b1 = bbF[chunk * 128 + 64 + lane];
        bool p0 = (b0.x <= txmax) & (b0.y >= txmin) & (b0.z <= tymax) & (b0.w >= tymin);
        bool p1 = (b1.x <= txmax) & (b1.y >= txmin) & (b1.z <= tymax) & (b1.w >= tymin);
        unsigned long long m0 = __ballot(p0);
        unsigned long long m1 = __ballot(p1);
        if (lane == 0) s_cnt[chunk] = __popcll(m0) + __popcll(m1);
        __syncthreads();
        int base = 0;
        for (int c = 0; c < chunk; ++c) base += s_cnt[c];
        totalA = s_cnt[0] + s_cnt[1] + s_cnt[2] + s_cnt[3];
        if (p0) s_listA[base + __popcll(m0 & ltmask)] = chunk * 128 + lane;
        if (p1) s_listA[base + __popcll(m0) + __popcll(m1 & ltmask)] = chunk * 128 + 64 + lane;
        __syncthreads();
    }

    // ---- Phase 1b: exact edge-vs-tile rejection, order-preserving ----
    int totalB = 0;
    for (int base = 0; base < totalA; base += 256) {
        int i = base + threadIdx.x;
        bool keep = false; int f = 0;
        if (i < totalA) {
            f = s_listA[i];
            const float* r = recF + ((size_t)f << 5);
            float sgn = r[5];
            float ax = r[8],  ay = r[9],  e2x = r[10], e2y = r[11];
            float bx = r[12], by = r[13], e0x = r[14], e0y = r[15];
            float cx = r[16], cy = r[17], e1x = r[18], e1y = r[19];
            float iL2 = r[24], iL0 = r[25], iL1 = r[26];
            // edge0: v=b, e=e0. g = ((px-vx)*ey - (py-vy)*ex)*sgn, maximized
            // over the tile square; reject if max < 0 and beyond MARGIN.
            float q0x = (fm(e0y, sgn) > 0.f) ? X1 : X0;
            float q0y = (fm(e0x, sgn) > 0.f) ? Y0 : Y1;
            float g0 = fm(fs2(fm(fs2(q0x, bx), e0y), fm(fs2(q0y, by), e0x)), sgn);
            bool rej0 = (g0 < 0.f) & (fm(fm(g0, g0), iL0) > MARGIN2);
            // edge1: v=c, e=e1
            float q1x = (fm(e1y, sgn) > 0.f) ? X1 : X0;
            float q1y = (fm(e1x, sgn) > 0.f) ? Y0 : Y1;
            float g1 = fm(fs2(fm(fs2(q1x, cx), e1y), fm(fs2(q1y, cy), e1x)), sgn);
            bool rej1 = (g1 < 0.f) & (fm(fm(g1, g1), iL1) > MARGIN2);
            // edge2: v=a, e=e2
            float q2x = (fm(e2y, sgn) > 0.f) ? X1 : X0;
            float q2y = (fm(e2x, sgn) > 0.f) ? Y0 : Y1;
            float g2 = fm(fs2(fm(fs2(q2x, ax), e2y), fm(fs2(q2y, ay), e2x)), sgn);
            bool rej2 = (g2 < 0.f) & (fm(fm(g2, g2), iL2) > MARGIN2);
            keep = !(rej0 | rej1 | rej2);
        }
        unsigned long long m = __ballot(keep);
        if (lane == 0) s_cnt[chunk] = __popcll(m);
        __syncthreads();
        int b2 = totalB;
        for (int c = 0; c < chunk; ++c) b2 += s_cnt[c];
        int roundTotal = s_cnt[0] + s_cnt[1] + s_cnt[2] + s_cnt[3];
        if (keep) s_listB[b2 + __popcll(m & ltmask)] = f;
        totalB += roundTotal;
        __syncthreads();
    }

    // ---- Phase 2: process refined list segment [lo,hi), ascending ----
    float bestScore = -1e30f;
    int best = -1;
    float bw0 = 0.f, bw1 = 0.f, bw2 = 0.f;
    float acc = 0.f;

    int lo = (totalB * chunk) >> 2;
    int hi = (totalB * (chunk + 1)) >> 2;
    for (int i = lo; i < hi; ++i) {
        int f = __builtin_amdgcn_readfirstlane(s_listB[i]);
        const float* r = recF + ((size_t)f << 5);
        float flag = r[4];
        float ax = r[8],  ay = r[9],  e2x = r[10], e2y = r[11];
        float bx = r[12], by = r[13], e0x = r[14], e0y = r[15];
        float cx = r[16], cy = r[17], e1x = r[18], e1y = r[19];
        float apx = fs2(px, ax), apy = fs2(py, ay);
        float bpx = fs2(px, bx), bpy = fs2(py, by);
        float cpx = fs2(px, cx), cpy = fs2(py, cy);
        // numerators in np's exact expression form (sign-exact inside test)
        float n0 = fs2(fm(bpx, e0y), fm(bpy, e0x));
        float n1 = fs2(fm(cpx, e1y), fm(cpy, e1x));
        float n2 = fs2(fm(apx, e2y), fm(apy, e2x));
        float sgn = r[5];
        bool inside = (flag == 1.f) & (fm(n0, sgn) >= 0.f)
                    & (fm(n1, sgn) >= 0.f) & (fm(n2, sgn) >= 0.f);
        if (inside) {
            float ia = r[6];
            float w0 = fm(n0, ia), w1v = fm(n1, ia), w2v = fm(n2, ia);
            float zpix = fa2(fa2(fm(w0, r[20]), fm(w1v, r[21])), fm(w2v, r[22]));
            if (zpix > bestScore) {  // strict > == np argmax first-max
                bestScore = zpix; best = f; bw0 = w0; bw1 = w1v; bw2 = w2v;
            }
            acc += LOG1M_CONST;      // d2=0 -> prob=0.9999
        } else {
            float t0 = fminf(fmaxf((apx * e2x + apy * e2y) * r[24], 0.f), 1.f);
            float dx0 = apx - t0 * e2x, dy0 = apy - t0 * e2y;
            float d2 = dx0 * dx0 + dy0 * dy0;
            float t1 = fminf(fmaxf((bpx * e0x + bpy * e0y) * r[25], 0.f), 1.f);
            float dx1 = bpx - t1 * e0x, dy1 = bpy - t1 * e0y;
            d2 = fminf(d2, dx1 * dx1 + dy1 * dy1);
            float t2 = fminf(fmaxf((cpx * e1x + cpy * e1y) * r[26], 0.f), 1.f);
            float dx2 = cpx - t2 * e1x, dy2 = cpy - t2 * e1y;
            d2 = fminf(d2, dx2 * dx2 + dy2 * dy2);
            if (d2 < D2_CUTOFF) {
                float pr = fminf(__expf(d2 * -7000.f), 0.9999f);
                acc += __logf(1.0f - pr);
            }
        }
    }

    s_score[threadIdx.x] = bestScore;
    s_best[threadIdx.x] = best;
    s_w0[threadIdx.x] = bw0; s_w1[threadIdx.x] = bw1; s_w2[threadIdx.x] = bw2;
    s_acc[threadIdx.x] = acc;
    __syncthreads();

    if (threadIdx.x < 64) {
        int i = threadIdx.x;   // chunk-0 thread: same pixel (p, px, py)
        bestScore = s_score[i]; best = s_best[i];
        bw0 = s_w0[i]; bw1 = s_w1[i]; bw2 = s_w2[i];
        acc = s_acc[i];
        for (int c = 1; c < 4; ++c) {   // ascending chunk order keeps first-max
            int j = c * 64 + i;
            float sc = s_score[j];
            if (sc > bestScore) {
                bestScore = sc; best = s_best[j];
                bw0 = s_w0[j]; bw1 = s_w1[j]; bw2 = s_w2[j];
            }
            acc += s_acc[j];
        }
        float fu = 0.f, fv = 0.f;
        if (best >= 0) {
            const float* fb = ffeat + best * 6;
            fu = bw0 * fb[0] + bw1 * fb[2] + bw2 * fb[4];
            fv = bw0 * fb[1] + bw1 * fb[3] + bw2 * fb[5];
        }
        float u = fminf(fmaxf(fu, 0.f), 1.f);
        float v = fminf(fmaxf(fv, 0.f), 1.f);
        float x = u * (float)TT - 0.5f;
        float y = (1.0f - v) * (float)TT - 0.5f;
        float x0f = floorf(x), y0f = floorf(y);
        float wx = x - x0f, wy = y - y0f;
        int x0 = min(max((int)x0f, 0), TT - 1);
        int x1 = min(x0 + 1, TT - 1);
        int y0 = min(max((int)y0f, 0), TT - 1);
        int y1 = min(y0 + 1, TT - 1);
        size_t obase = (size_t)frame * 5 * 16384 + p;
        for (int c = 0; c < 3; ++c) {
            const float* tc = tex + c * (TT * TT);
            float t00 = tc[y0 * TT + x0];
            float t01 = tc[y0 * TT + x1];
            float t10 = tc[y1 * TT + x0];
            float t11 = tc[y1 * TT + x1];
            float rgb = (1.f - wy) * ((1.f - wx) * t00 + wx * t01)
                      + wy * ((1.f - wx) * t10 + wx * t11);
            out[obase + (size_t)c * 16384] = rgb;
        }
        int redw = (best >= 0) ? best : (NFACE - 1);
        const float* rr = recF + ((size_t)redw << 5);
        float depth = fd2(fa2(fa2(rr[20], rr[21]), rr[22]), 3.0f);
        out[obase + 4ull * 16384] = depth;
        float soft = 1.0f - __expf(acc);
        softbuf[frame * 16384 + p] = soft;
    }
}

// ---------------- Kernel 3: 7x7 min-pool (pad = +inf identity) ----------------
__global__ void minpool_kernel(const float* __restrict__ softbuf,
                               float* __restrict__ out) {
    int idx = blockIdx.x * 256 + threadIdx.x;
    if (idx >= NFRM * 16384) return;
    int frame = idx >> 14;
    int p = idx & 16383;
    int h = p >> 7, w = p & 127;
    const float* sb = softbuf + frame * 16384;
    float m = INFINITY;
    int h0 = max(h - 3, 0), h1 = min(h + 3, 127);
    int w0 = max(w - 3, 0), w1 = min(w + 3, 127);
    for (int hh = h0; hh <= h1; ++hh)
        for (int ww = w0; ww <= w1; ++ww)
            m = fminf(m, sb[hh * 128 + ww]);
    out[(size_t)frame * 5 * 16384 + 3ull * 16384 + p] = m;
}

// ---------------- launch ----------------
extern "C" void kernel_launch(void* const* d_in, const int* in_sizes, int n_in,
                              void* d_out, int out_size, void* d_ws, size_t ws_size,
                              hipStream_t stream) {
    const float* trans  = (const float*)d_in[0]; // (1,1,4,3)
    const float* quat   = (const float*)d_in[1]; // (1,4,4)
    const float* uverts = (const float*)d_in[2]; // (1,256,3)
    const float* ffeat  = (const float*)d_in[3]; // (1,512,3,2)
    const float* tex    = (const float*)d_in[4]; // (1,3,256,256)
    const int*   faces  = (const int*)d_in[5];   // (512,3)
    float* out = (float*)d_out;                  // (1,4,1,5,128,128) fp32

    float* recs    = (float*)d_ws;                         // 4*512*32 f = 256 KB
    float4* bbox4  = (float4*)(recs + NFRM * NFACE * REC); // 4*512 f4 = 32 KB
    float* softbuf = (float*)(bbox4 + NFRM * NFACE);       // 4*16384 floats

    setup_kernel<<<(NFRM * NFACE + 255) / 256, 256, 0, stream>>>(
        trans, quat, uverts, faces, recs, bbox4);
    raster_kernel<<<NFRM * 256, 256, 0, stream>>>(
        recs, bbox4, ffeat, tex, out, softbuf);
    minpool_kernel<<<(NFRM * 16384) / 256, 256, 0, stream>>>(softbuf, out);
}